// Round 4
// baseline (219.000 us; speedup 1.0000x reference)
//
#include <hip/hip_runtime.h>

#define N_Q 50000
#define H_NB 32
#define K_KP 15
#define C_CH 128
#define KP_EXT 1.2f

__global__ __launch_bounds__(128, 4)
void kpconv_dw_kernel(const float* __restrict__ q_pts,
                      const float* __restrict__ s_pts,
                      const int*   __restrict__ inds,
                      const float* __restrict__ x,
                      const float* __restrict__ kp,
                      const float* __restrict__ dw,
                      const float* __restrict__ bias,
                      float*       __restrict__ out)
{
    __shared__ int   s_idx[H_NB];
    __shared__ float s_pos[H_NB][3];
    __shared__ float s_kp[K_KP * 3];
    __shared__ __align__(16) float s_w[H_NB][16];   // k=0..14 + pad (zeroed)

    const int n = blockIdx.x;
    const int t = threadIdx.x;

    if (t < K_KP * 3) s_kp[t] = kp[t];

    if (t < H_NB) {
        const float qx = q_pts[n * 3 + 0];
        const float qy = q_pts[n * 3 + 1];
        const float qz = q_pts[n * 3 + 2];
        int idx = inds[n * H_NB + t];
        s_idx[t] = idx;
        s_pos[t][0] = s_pts[idx * 3 + 0] - qx;
        s_pos[t][1] = s_pts[idx * 3 + 1] - qy;
        s_pos[t][2] = s_pts[idx * 3 + 2] - qz;
        s_w[t][15] = 0.0f;                          // pad slot: must not be NaN poison
    }
    __syncthreads();

    for (int p = t; p < H_NB * K_KP; p += 128) {
        const int h = p / K_KP;
        const int k = p - h * K_KP;
        const float dx = s_pos[h][0] - s_kp[k * 3 + 0];
        const float dy = s_pos[h][1] - s_kp[k * 3 + 1];
        const float dz = s_pos[h][2] - s_kp[k * 3 + 2];
        const float d = sqrtf(fmaf(dx, dx, fmaf(dy, dy, dz * dz)));
        const float w = 1.0f - d * (1.0f / KP_EXT);
        s_w[h][k] = w > 0.0f ? w : 0.0f;
    }
    __syncthreads();

    const int c = t;

    float dwr[16];
#pragma unroll
    for (int k = 0; k < K_KP; ++k) dwr[k] = dw[k * C_CH + c];
    dwr[15] = 0.0f;

    // prefetch ALL 32 gathered features — 32 loads in flight, latency hidden
    // under the 544-FMA dot phase below
    float xv[H_NB];
    const float* __restrict__ xc = x + c;
#pragma unroll
    for (int h = 0; h < H_NB; ++h) {
        xv[h] = xc[(long)s_idx[h] * C_CH];
    }

    float acc = bias[c];
#pragma unroll
    for (int h = 0; h < H_NB; ++h) {
        const float4* wp = (const float4*)s_w[h];   // 4x ds_read_b128, broadcast
        const float4 w0 = wp[0];
        const float4 w1 = wp[1];
        const float4 w2 = wp[2];
        const float4 w3 = wp[3];
        float cw;
        cw = w0.x * dwr[0];
        cw = fmaf(w0.y, dwr[1],  cw);
        cw = fmaf(w0.z, dwr[2],  cw);
        cw = fmaf(w0.w, dwr[3],  cw);
        cw = fmaf(w1.x, dwr[4],  cw);
        cw = fmaf(w1.y, dwr[5],  cw);
        cw = fmaf(w1.z, dwr[6],  cw);
        cw = fmaf(w1.w, dwr[7],  cw);
        cw = fmaf(w2.x, dwr[8],  cw);
        cw = fmaf(w2.y, dwr[9],  cw);
        cw = fmaf(w2.z, dwr[10], cw);
        cw = fmaf(w2.w, dwr[11], cw);
        cw = fmaf(w3.x, dwr[12], cw);
        cw = fmaf(w3.y, dwr[13], cw);
        cw = fmaf(w3.z, dwr[14], cw);
        // w3.w * dwr[15] == x * 0, both zeroed — skip
        acc = fmaf(cw, xv[h], acc);
    }
    out[n * C_CH + c] = acc;
}

extern "C" void kernel_launch(void* const* d_in, const int* in_sizes, int n_in,
                              void* d_out, int out_size, void* d_ws, size_t ws_size,
                              hipStream_t stream) {
    const float* q_pts = (const float*)d_in[0];
    const float* s_pts = (const float*)d_in[1];
    const int*   inds  = (const int*)  d_in[2];
    const float* x     = (const float*)d_in[3];
    const float* kp    = (const float*)d_in[4];
    const float* dw    = (const float*)d_in[5];
    const float* bias  = (const float*)d_in[6];
    float* out = (float*)d_out;

    kpconv_dw_kernel<<<N_Q, 128, 0, stream>>>(q_pts, s_pts, inds, x, kp, dw, bias, out);
}

// Round 5
// 197.853 us; speedup vs baseline: 1.1069x; 1.1069x over previous
//
#include <hip/hip_runtime.h>
#include <hip/hip_bf16.h>

#define N_Q 50000
#define H_NB 32
#define K_KP 15
#define C_CH 128
#define KP_EXT 1.2f

typedef __attribute__((ext_vector_type(8))) short bf16x8;   // MFMA A/B operand (8 bf16)
typedef __attribute__((ext_vector_type(4))) float f32x4;    // MFMA C/D

static __device__ __forceinline__ short f2bf(float f) {
    __hip_bfloat16 h = __float2bfloat16(f);   // RNE convert
    return *reinterpret_cast<short*>(&h);
}

// One wave per query point. Per point: P[k,c] = sum_h w[h,k] * x[idx_h, c]
// as an M=16(k) x N=128(c, 8 tiles) x K=32(h) bf16 MFMA, then
// out[c] = sum_k dw[k,c] * P[k,c] + bias[c] as a 4-FMA + butterfly epilogue.
// A-fragment layout (16x16x32): lane l holds A[row=l&15][kdim=(l>>4)*8+j], so
// lane l computes w for kernel-point k=l&15 and neighbors h=(l>>4)*8+j directly
// (no LDS, no broadcast). B: lane l holds B[kdim=(l>>4)*8+j][col=l&15].
// C/D: col=l&15, row=(l>>4)*4+r  [verified layout, learn_hip m89/m91].
__global__ __launch_bounds__(256, 4)
void kpconv_mfma_kernel(const float* __restrict__ q_pts,
                        const float* __restrict__ s_pts,
                        const int*   __restrict__ inds,
                        const float* __restrict__ x,
                        const float* __restrict__ kp,
                        const float* __restrict__ dw,
                        const float* __restrict__ bias,
                        float*       __restrict__ out)
{
    const int wave = threadIdx.x >> 6;
    const int l    = threadIdx.x & 63;
    const int n    = blockIdx.x * 4 + wave;     // grid is exact: 12500*4 = 50000

    const int lg = l >> 4;                      // lane group 0..3 -> h block
    const int ln = l & 15;                      // 0..15 -> k (A) / col (B,C)

    // this lane's 8 neighbor indices: h = lg*8 + j   (32B-aligned int4 pair)
    const int4* ip = reinterpret_cast<const int4*>(inds + n * H_NB + lg * 8);
    const int4 i0 = ip[0];
    const int4 i1 = ip[1];
    const int idxv[8] = {i0.x, i0.y, i0.z, i0.w, i1.x, i1.y, i1.z, i1.w};

    // query point (wave-uniform address -> one cache line)
    const float qx = q_pts[n*3+0], qy = q_pts[n*3+1], qz = q_pts[n*3+2];

    // kernel point for this lane's k = ln  (k=15 is pad: clamp load, zero w)
    const int kkc = ln < K_KP ? ln : (K_KP - 1);
    const float kpx = kp[kkc*3+0], kpy = kp[kkc*3+1], kpz = kp[kkc*3+2];

    // ---- A fragment: w[h][k] in bf16, computed in-register ----
    bf16x8 afrag;
#pragma unroll
    for (int j = 0; j < 8; ++j) {
        const int idx = idxv[j];
        const float px = s_pts[idx*3+0] - qx;
        const float py = s_pts[idx*3+1] - qy;
        const float pz = s_pts[idx*3+2] - qz;
        const float dx = px - kpx, dy = py - kpy, dz = pz - kpz;
        const float d  = sqrtf(fmaf(dx, dx, fmaf(dy, dy, dz*dz)));
        float w = fmaxf(1.0f - d * (1.0f/KP_EXT), 0.0f);
        if (ln == 15) w = 0.0f;                 // pad kernel-point row
        afrag[j] = f2bf(w);
    }

    // gathered-x element offsets (32-bit: max 50000*128 < 2^31)
    unsigned boff[8];
#pragma unroll
    for (int j = 0; j < 8; ++j) boff[j] = (unsigned)idxv[j] * C_CH + (unsigned)ln;

    f32x4 acc[8];
#pragma unroll
    for (int t = 0; t < 8; ++t) acc[t] = (f32x4){0.f, 0.f, 0.f, 0.f};

    // ---- 8 column tiles: gather 8 x values, cvt to bf16, MFMA ----
#pragma unroll
    for (int t = 0; t < 8; ++t) {
        float xf[8];
#pragma unroll
        for (int j = 0; j < 8; ++j) xf[j] = x[boff[j] + t*16];
        bf16x8 bfrag;
#pragma unroll
        for (int j = 0; j < 8; ++j) bfrag[j] = f2bf(xf[j]);
        acc[t] = __builtin_amdgcn_mfma_f32_16x16x32_bf16(afrag, bfrag, acc[t], 0, 0, 0);
    }

    // ---- epilogue: out[c] = sum_k dw[k,c]*P[k,c] + bias[c] ----
    const int rowbase = lg * 4;
#pragma unroll
    for (int t = 0; t < 8; ++t) {
        const int c = t*16 + ln;
        float s = 0.f;
#pragma unroll
        for (int r = 0; r < 4; ++r) {
            const int row = rowbase + r;
            float dwv = dw[(row < K_KP ? row : (K_KP-1)) * C_CH + c];
            if (row >= K_KP) dwv = 0.f;         // pad row (P there is 0 anyway)
            s = fmaf(dwv, acc[t][r], s);
        }
        s += __shfl_xor(s, 16);                 // sum over the 4 row-groups
        s += __shfl_xor(s, 32);
        s += bias[c];
        if (l < 16) out[n * C_CH + c] = s;
    }
}

extern "C" void kernel_launch(void* const* d_in, const int* in_sizes, int n_in,
                              void* d_out, int out_size, void* d_ws, size_t ws_size,
                              hipStream_t stream) {
    const float* q_pts = (const float*)d_in[0];
    const float* s_pts = (const float*)d_in[1];
    const int*   inds  = (const int*)  d_in[2];
    const float* x     = (const float*)d_in[3];
    const float* kp    = (const float*)d_in[4];
    const float* dw    = (const float*)d_in[5];
    const float* bias  = (const float*)d_in[6];
    float* out = (float*)d_out;

    kpconv_mfma_kernel<<<N_Q / 4, 256, 0, stream>>>(q_pts, s_pts, inds, x, kp, dw, bias, out);
}